// Round 7
// baseline (267.813 us; speedup 1.0000x reference)
//
#include <hip/hip_runtime.h>
#include <hip/hip_bf16.h>

typedef unsigned short ushort_t;
typedef __bf16 bf16x8 __attribute__((ext_vector_type(8)));
typedef unsigned short us8 __attribute__((ext_vector_type(8)));
typedef float f32x4 __attribute__((ext_vector_type(4)));

__device__ __forceinline__ float b2f(ushort_t h) {
    union { unsigned int u; float f; } v; v.u = ((unsigned int)h) << 16; return v.f;
}
__device__ __forceinline__ ushort_t f2b(float f) {
    union { float f; unsigned int u; } v; v.f = f;
    unsigned int u = v.u;
    unsigned int r = (u + 0x7FFFu + ((u >> 16) & 1u)) >> 16;
    return (ushort_t)r;
}
__device__ __forceinline__ float sigmoidf_(float x) {
    return 1.f / (1.f + __expf(-x));
}
__device__ __forceinline__ void store_o(ushort_t* p, float v) { *p = f2b(v); }
__device__ __forceinline__ void store_o(float* p, float v) { *p = v; }

__global__ void fill_kernel(float* out, long long n, float val) {
    long long i = (long long)blockIdx.x * blockDim.x + threadIdx.x;
    if (i < n) out[i] = val;
}

// ---------------------------------------------------------------------------
// Packed B layout for mfma_f32_16x16x32_bf16, per 64-col block c and 32-k
// group kk: 4 col-subtiles s (16 cols), 64 lanes (lane = q*16 + n, q = k-oct,
// n = col&15), 8 contiguous bf16 (k&7). A wave's fragment load = 64 lanes x
// 16 B contiguous = 1 KB, perfectly coalesced. Subtile stride 512 ushorts,
// kk-group stride 2048.
// ---------------------------------------------------------------------------
#define PACKSZ(O, K) ((long long)((O) >= 64 ? (O) >> 6 : 1) * ((K) >> 5) * 2048)

// ---------------------------------------------------------------------------
// Sort rows by agent id (1 block) + emit BM=64 tile table.
// ---------------------------------------------------------------------------
__global__ void sort_kernel(const int* __restrict__ ids, int N,
                            int* __restrict__ perm, int* __restrict__ seg,
                            int4* __restrict__ ttab, int* __restrict__ tcount) {
    __shared__ int cnt[8];
    __shared__ int off[8];
    int tid = threadIdx.x;
    if (tid < 8) cnt[tid] = 0;
    __syncthreads();
    for (int n = tid; n < N; n += blockDim.x) atomicAdd(&cnt[ids[n] & 7], 1);
    __syncthreads();
    if (tid == 0) {
        int s = 0;
        for (int a = 0; a < 8; a++) { off[a] = s; seg[a] = s; s += cnt[a]; }
        seg[8] = s;
        int T = 0;
        for (int a = 0; a < 8; a++)
            for (int m = seg[a]; m < seg[a + 1]; m += 64) {
                int e = seg[a + 1] < m + 64 ? seg[a + 1] : m + 64;
                ttab[T++] = make_int4(a, m, e, 0);
            }
        *tcount = T;
    }
    __syncthreads();
    for (int n = tid; n < N; n += blockDim.x) {
        int p = atomicAdd(&off[ids[n] & 7], 1);
        perm[p] = n;
    }
}

// ---------------------------------------------------------------------------
// Fused prep: masked weights -> packed-B bf16; activations gathered to
// pos-order bf16; GRU weights -> packed-B bf16.
// ---------------------------------------------------------------------------
__device__ __forceinline__ void maskw_item(const float* __restrict__ alpha,
                                           const float* __restrict__ w,
                                           ushort_t* __restrict__ wm,
                                           long long idx, int O, int G, int dup) {
    int g = (int)(idx % G);
    long long t2 = idx / G;
    int o = (int)(t2 % O);
    int a = (int)(t2 / O);
    const float* al = alpha + idx * 6;
    float p[6];
    float mx = -1e30f;
    #pragma unroll
    for (int i = 0; i < 6; i++) { p[i] = al[i] * 0.2f; mx = fmaxf(mx, p[i]); }
    float s = 0.f;
    #pragma unroll
    for (int i = 0; i < 6; i++) { p[i] = __expf(p[i] - mx); s += p[i]; }
    float inv = 1.f / s;
    #pragma unroll
    for (int i = 0; i < 6; i++) p[i] *= inv;
    float mk[4] = { p[0] + p[1] + p[2], p[0] + p[3] + p[4],
                    p[1] + p[3] + p[5], p[2] + p[4] + p[5] };
    int K = G * 4;
    const float* wr = w + (long long)o * K + g * 4;
    ushort_t* base = wm + (long long)a * PACKSZ(O, K);
    int k0 = g * 4;
    int c = o >> 6, su = (o >> 4) & 3, n = o & 15;
    int kk = k0 >> 5, q = (k0 >> 3) & 3, e0 = k0 & 7;
    long long off = (((long long)(c * (K >> 5) + kk) * 4 + su) * 64 + (q * 16 + n)) * 8 + e0;
    #pragma unroll
    for (int t = 0; t < 4; t++) {
        ushort_t v = f2b(wr[t] * mk[t]);
        base[off + t] = v;
        if (dup) {              // O=16: replicate into s=1..3 slots (discarded at store)
            base[off + t + 512] = v;
            base[off + t + 1024] = v;
            base[off + t + 1536] = v;
        }
    }
}

__device__ __forceinline__ void canon_gather_item(const float* __restrict__ src,
                                                  ushort_t* __restrict__ dst,
                                                  const int* __restrict__ perm,
                                                  int ld, long long i) {
    long long base = i * 8;
    int pos = (int)(base / ld);
    int k = (int)(base % ld);
    int row = perm[pos] & 8191;
    const float* s = src + (long long)row * ld + k;
    us8 v;
    #pragma unroll
    for (int e = 0; e < 8; e++) v[e] = f2b(s[e]);
    *(us8*)(dst + base) = v;
}

__device__ __forceinline__ void canon_pack_item(const float* __restrict__ src,
                                                ushort_t* __restrict__ dst,
                                                long long i) {
    // src: [1536,512] fp32 -> dst: 3 gates x packed(512,512)
    long long base = i * 8;
    int o_full = (int)(base >> 9);
    int k0 = (int)(base & 511);
    int g = o_full >> 9, o = o_full & 511;
    int c = o >> 6, su = (o >> 4) & 3, n = o & 15;
    int kk = k0 >> 5, q = (k0 >> 3) & 3;
    long long off = (long long)g * 262144 +
        (((long long)(c * 16 + kk) * 4 + su) * 64 + (q * 16 + n)) * 8;
    us8 v;
    #pragma unroll
    for (int e = 0; e < 8; e++) v[e] = f2b(src[base + e]);
    *(us8*)(dst + off) = v;
}

#define PB0 256    // maskw fc1  (65536 items)
#define PB1 2048   // maskw fc2  (524288)
#define PB2 2048   // maskw fc3  (524288)
#define PB3 64     // maskw fc4  (16384)
#define PB4 256    // gather-canon inputs (65536 x8)
#define PB5 2048   // gather-canon hidden (524288 x8)
#define PB6 384    // pack-canon wih (98304 x8)
#define PB7 384    // pack-canon whh (98304 x8)
#define PREP_BLOCKS (PB0+PB1+PB2+PB3+PB4+PB5+PB6+PB7)

__global__ void prep_kernel(const float* fc1_al, const float* fc1_w, ushort_t* wm1,
                            const float* fc2_al, const float* fc2_w, ushort_t* wm2,
                            const float* fc3_al, const float* fc3_w, ushort_t* wm3,
                            const float* fc4_al, const float* fc4_w, ushort_t* wm4,
                            const float* inputs, ushort_t* inp_pos,
                            const float* hidden, ushort_t* hid_pos,
                            const float* wih, ushort_t* wihp,
                            const float* whh, ushort_t* whhp,
                            const int* perm) {
    int b = blockIdx.x;
    int tid = threadIdx.x;
    if (b < PB0) { maskw_item(fc1_al, fc1_w, wm1, (long long)b * 256 + tid, 512, 16, 0); return; }
    b -= PB0;
    if (b < PB1) { maskw_item(fc2_al, fc2_w, wm2, (long long)b * 256 + tid, 512, 128, 0); return; }
    b -= PB1;
    if (b < PB2) { maskw_item(fc3_al, fc3_w, wm3, (long long)b * 256 + tid, 512, 128, 0); return; }
    b -= PB2;
    if (b < PB3) { maskw_item(fc4_al, fc4_w, wm4, (long long)b * 256 + tid, 16, 128, 1); return; }
    b -= PB3;
    if (b < PB4) { canon_gather_item(inputs, inp_pos, perm, 64, (long long)b * 256 + tid); return; }
    b -= PB4;
    if (b < PB5) { canon_gather_item(hidden, hid_pos, perm, 512, (long long)b * 256 + tid); return; }
    b -= PB5;
    if (b < PB6) { canon_pack_item(wih, wihp, (long long)b * 256 + tid); return; }
    b -= PB6;
    canon_pack_item(whh, whhp, (long long)b * 256 + tid);
}

// ---------------------------------------------------------------------------
// GEMM: A (pos-order, bf16) staged via swizzled LDS (4 KB); B streamed from
// packed global (L2-resident) straight into MFMA fragments.
// ---------------------------------------------------------------------------
#define BM 64
#define BN 64

template <typename OT>
__launch_bounds__(256, 4)
__global__ void gemm_tiled(const ushort_t* __restrict__ In, int ldin,
                           const ushort_t* __restrict__ Wpk, long long wstride,
                           const float* __restrict__ bias,
                           OT* __restrict__ Out, int ldo,
                           const int4* __restrict__ ttab,
                           const int* __restrict__ tcount,
                           const int* __restrict__ scatter,
                           int O, int K, int relu) {
    int t = blockIdx.x;
    if (t >= *tcount) return;
    int4 tt = ttab[t];
    int a = tt.x, pos0 = tt.y, pos1 = tt.z;
    int o0 = blockIdx.y * BN;

    __shared__ ushort_t As[2048];

    int tid = threadIdx.x;
    int wave = tid >> 6, lane = tid & 63;
    int wr = (wave >> 1) & 1, wc = wave & 1;
    int quad = lane >> 4, l16 = lane & 15;
    int srow = tid >> 2, sgrp = tid & 3;
    int wsoff = (srow * 4 + (sgrp ^ ((srow >> 2) & 3))) * 8;
    int rl = (l16 * 4 + (quad ^ ((l16 >> 2) & 3))) * 8;

    int apos = pos0 + srow;
    int apos_c = apos < pos1 ? apos : (pos1 - 1);
    const ushort_t* aptr = In + (long long)apos_c * ldin + sgrp * 8;

    // packed B base: agent a, col-block blockIdx.y, this lane
    const ushort_t* wb = Wpk + (long long)a * wstride +
        (long long)blockIdx.y * (K >> 5) * 2048 + lane * 8;

    f32x4 acc[2][2];
    #pragma unroll
    for (int i = 0; i < 2; i++)
        #pragma unroll
        for (int j = 0; j < 2; j++) acc[i][j] = (f32x4){0.f, 0.f, 0.f, 0.f};

    int KK = K >> 5;
    for (int kk = 0; kk < KK; kk++) {
        us8 av = *(const us8*)(aptr + kk * 32);
        bf16x8 bfr[2];
        bfr[0] = *(const bf16x8*)(wb + (kk * 4 + wc * 2 + 0) * 512);
        bfr[1] = *(const bf16x8*)(wb + (kk * 4 + wc * 2 + 1) * 512);
        __syncthreads();
        *(us8*)(&As[wsoff]) = av;
        __syncthreads();
        bf16x8 af[2];
        af[0] = *(const bf16x8*)(&As[(wr * 2 + 0) * 512 + rl]);
        af[1] = *(const bf16x8*)(&As[(wr * 2 + 1) * 512 + rl]);
        #pragma unroll
        for (int i = 0; i < 2; i++)
            #pragma unroll
            for (int j = 0; j < 2; j++)
                acc[i][j] = __builtin_amdgcn_mfma_f32_16x16x32_bf16(af[i], bfr[j], acc[i][j], 0, 0, 0);
    }

    #pragma unroll
    for (int i = 0; i < 2; i++) {
        int mbase = wr * 32 + i * 16 + quad * 4;
        #pragma unroll
        for (int j = 0; j < 2; j++) {
            int col = o0 + wc * 32 + j * 16 + l16;
            if (col < O) {
                float bias_v = bias ? bias[col] : 0.f;
                #pragma unroll
                for (int r = 0; r < 4; r++) {
                    int pos = pos0 + mbase + r;
                    if (pos < pos1) {
                        float v = acc[i][j][r] + bias_v;
                        if (relu) v = fmaxf(v, 0.f);
                        int orow = (scatter ? scatter[pos] : pos) & 8191;
                        store_o(&Out[(long long)orow * ldo + col], v);
                    }
                }
            }
        }
    }
}

// ---------------------------------------------------------------------------
// Fused GRU: A (y1, hid_pos — both pos-order) via 8 KB LDS; 6 gate B-operands
// streamed from packed global (L2). Gate math in epilogue.
// ---------------------------------------------------------------------------
__launch_bounds__(256, 2)
__global__ void gru_fused(const ushort_t* __restrict__ y1,       // [N,H] pos bf16
                          const ushort_t* __restrict__ hid_pos,  // [N,H] pos bf16
                          const float* __restrict__ hidden_f,    // [N,H] orig fp32
                          const ushort_t* __restrict__ wihp,     // packed 3x(512,512)
                          const ushort_t* __restrict__ whhp,     // packed 3x(512,512)
                          const float* __restrict__ bih,
                          const float* __restrict__ bhh,
                          const int* __restrict__ perm,
                          float* __restrict__ out_h_f,           // [N,H] orig fp32
                          ushort_t* __restrict__ hp,             // [N,H] pos bf16
                          int N, int H) {
    int m0 = blockIdx.x * 64;

    __shared__ ushort_t Ay[2048];
    __shared__ ushort_t Ah[2048];

    int tid = threadIdx.x;
    int wave = tid >> 6, lane = tid & 63;
    int wr = (wave >> 1) & 1, wc = wave & 1;
    int quad = lane >> 4, l16 = lane & 15;
    int srow = tid >> 2, sgrp = tid & 3;
    int wsoff = (srow * 4 + (sgrp ^ ((srow >> 2) & 3))) * 8;
    int rl = (l16 * 4 + (quad ^ ((l16 >> 2) & 3))) * 8;

    const ushort_t* ay_p = y1 + (long long)(m0 + srow) * H + sgrp * 8;
    const ushort_t* ah_p = hid_pos + (long long)(m0 + srow) * H + sgrp * 8;

    // packed B bases (c-block = blockIdx.y), this lane
    long long cb = (long long)blockIdx.y * 16 * 2048 + lane * 8;
    const ushort_t* wb[6];
    #pragma unroll
    for (int g = 0; g < 3; g++) wb[g] = wihp + (long long)g * 262144 + cb;
    #pragma unroll
    for (int g = 3; g < 6; g++) wb[g] = whhp + (long long)(g - 3) * 262144 + cb;

    f32x4 acc[6][2][2];
    #pragma unroll
    for (int g = 0; g < 6; g++)
        #pragma unroll
        for (int i = 0; i < 2; i++)
            #pragma unroll
            for (int j = 0; j < 2; j++) acc[g][i][j] = (f32x4){0.f, 0.f, 0.f, 0.f};

    for (int kk = 0; kk < 16; kk++) {
        us8 va = *(const us8*)(ay_p + kk * 32);
        us8 vh = *(const us8*)(ah_p + kk * 32);
        __syncthreads();
        *(us8*)(&Ay[wsoff]) = va;
        *(us8*)(&Ah[wsoff]) = vh;
        __syncthreads();

        bf16x8 ayf[2], ahf[2];
        #pragma unroll
        for (int u = 0; u < 2; u++) {
            ayf[u] = *(const bf16x8*)(&Ay[(wr * 2 + u) * 512 + rl]);
            ahf[u] = *(const bf16x8*)(&Ah[(wr * 2 + u) * 512 + rl]);
        }
        int fo = (kk * 4 + wc * 2) * 512;
        #pragma unroll
        for (int g = 0; g < 6; g++) {
            bf16x8 bfr[2];
            bfr[0] = *(const bf16x8*)(wb[g] + fo);
            bfr[1] = *(const bf16x8*)(wb[g] + fo + 512);
            #pragma unroll
            for (int i = 0; i < 2; i++)
                #pragma unroll
                for (int j = 0; j < 2; j++)
                    acc[g][i][j] = __builtin_amdgcn_mfma_f32_16x16x32_bf16(
                        (g < 3) ? ayf[i] : ahf[i], bfr[j], acc[g][i][j], 0, 0, 0);
        }
    }

    int c0 = blockIdx.y * 64;
    #pragma unroll
    for (int i = 0; i < 2; i++) {
        #pragma unroll
        for (int r = 0; r < 4; r++) {
            int pos = m0 + wr * 32 + i * 16 + quad * 4 + r;
            int norig = perm[pos] & 8191;
            #pragma unroll
            for (int j = 0; j < 2; j++) {
                int col = c0 + wc * 32 + j * 16 + l16;
                float ir = acc[0][i][j][r] + bih[col];
                float iz = acc[1][i][j][r] + bih[H + col];
                float in_ = acc[2][i][j][r] + bih[2 * H + col];
                float hr = acc[3][i][j][r] + bhh[col];
                float hz = acc[4][i][j][r] + bhh[H + col];
                float hn = acc[5][i][j][r] + bhh[2 * H + col];
                float rg = sigmoidf_(ir + hr);
                float zg = sigmoidf_(iz + hz);
                float ng = tanhf(in_ + rg * hn);
                float hv = hidden_f[(long long)norig * H + col];
                float hnew = (1.f - zg) * ng + zg * hv;
                out_h_f[(long long)norig * H + col] = hnew;
                hp[(long long)pos * H + col] = f2b(hnew);
            }
        }
    }
}

// ---------------------------------------------------------------------------
extern "C" void kernel_launch(void* const* d_in, const int* in_sizes, int n_in,
                              void* d_out, int out_size, void* d_ws, size_t ws_size,
                              hipStream_t stream) {
    (void)in_sizes; (void)n_in;
    const int N = 8192, A = 8, E = 64, H = 512, NA = 16;

    float* out_f = (float*)d_out;
    float* out_q = out_f;                        // [N, NA] fp32
    float* out_h = out_f + (size_t)N * NA;       // [N, H] fp32, original order

    char* p = (char*)d_ws;
    auto alloc = [&](size_t b) { char* r = p; p += (b + 255) & ~(size_t)255; return r; };
    int*  perm   = (int*)alloc((size_t)N * 4);
    int*  seg    = (int*)alloc(16 * 4);
    int4* ttab   = (int4*)alloc(144 * 16);
    int*  tcount = (int*)alloc(256);
    ushort_t* wm1     = (ushort_t*)alloc((size_t)A * PACKSZ(H, E) * 2);    // 512 KB
    ushort_t* wm2     = (ushort_t*)alloc((size_t)A * PACKSZ(H, H) * 2);    // 4 MB
    ushort_t* wm3     = (ushort_t*)alloc((size_t)A * PACKSZ(H, H) * 2);    // 4 MB
    ushort_t* wm4     = (ushort_t*)alloc((size_t)A * PACKSZ(NA, H) * 2);   // 512 KB
    ushort_t* y1      = (ushort_t*)alloc((size_t)N * H * 2);               // 8 MB
    ushort_t* inp_pos = (ushort_t*)alloc((size_t)N * E * 2);               // 1 MB
    ushort_t* hid_pos = (ushort_t*)alloc((size_t)N * H * 2);               // 8 MB
    ushort_t* wihp    = (ushort_t*)alloc((size_t)3 * H * H * 2);           // 1.5 MB
    ushort_t* whhp    = (ushort_t*)alloc((size_t)3 * H * H * 2);           // 1.5 MB
    ushort_t* hp      = (ushort_t*)alloc((size_t)N * H * 2);               // 8 MB
    size_t need = (size_t)(p - (char*)d_ws);
    ushort_t* q2 = y1;       // alias: y1 dead after gru_fused
    ushort_t* q3 = hid_pos;  // alias: hid_pos dead after gru_fused

    if (ws_size < need) {
        fill_kernel<<<(unsigned)((out_size + 255) / 256), 256, 0, stream>>>(
            out_f, out_size, 1000.f);
        return;
    }

    const float* inputs = (const float*)d_in[0];
    const float* hidden = (const float*)d_in[1];
    const int*   ids    = (const int*)d_in[2];
    const float* fc1_w  = (const float*)d_in[3];
    const float* fc1_b  = (const float*)d_in[4];
    const float* fc1_al = (const float*)d_in[5];
    const float* wih    = (const float*)d_in[6];
    const float* whh    = (const float*)d_in[7];
    const float* bih    = (const float*)d_in[8];
    const float* bhh    = (const float*)d_in[9];
    const float* fc2_w  = (const float*)d_in[10];
    const float* fc2_b  = (const float*)d_in[11];
    const float* fc2_al = (const float*)d_in[12];
    const float* fc3_w  = (const float*)d_in[13];
    const float* fc3_b  = (const float*)d_in[14];
    const float* fc3_al = (const float*)d_in[15];
    const float* fc4_w  = (const float*)d_in[16];
    const float* fc4_b  = (const float*)d_in[17];
    const float* fc4_al = (const float*)d_in[18];

    sort_kernel<<<1, 1024, 0, stream>>>(ids, N, perm, seg, ttab, tcount);

    prep_kernel<<<PREP_BLOCKS, 256, 0, stream>>>(
        fc1_al, fc1_w, wm1, fc2_al, fc2_w, wm2, fc3_al, fc3_w, wm3,
        fc4_al, fc4_w, wm4, inputs, inp_pos, hidden, hid_pos,
        wih, wihp, whh, whhp, perm);

    dim3 blk(256);
    // fc1 -> y1 (pos, bf16), relu
    gemm_tiled<ushort_t><<<dim3(136, H / BN), blk, 0, stream>>>(
        inp_pos, E, wm1, PACKSZ(H, E), fc1_b, y1, H, ttab, tcount,
        nullptr, H, E, 1);
    // fused GRU -> out_h (fp32, orig) + hp (bf16, pos)
    gru_fused<<<dim3(N / 64, H / 64), blk, 0, stream>>>(
        y1, hid_pos, hidden, wihp, whhp, bih, bhh, perm, out_h, hp, N, H);
    // fc2 -> q2, relu
    gemm_tiled<ushort_t><<<dim3(136, H / BN), blk, 0, stream>>>(
        hp, H, wm2, PACKSZ(H, H), fc2_b, q2, H, ttab, tcount,
        nullptr, H, H, 1);
    // fc3 -> q3, relu
    gemm_tiled<ushort_t><<<dim3(136, H / BN), blk, 0, stream>>>(
        q2, H, wm3, PACKSZ(H, H), fc3_b, q3, H, ttab, tcount,
        nullptr, H, H, 1);
    // fc4 -> out_q (fp32, orig order via perm scatter)
    gemm_tiled<float><<<dim3(136, 1), blk, 0, stream>>>(
        q3, H, wm4, PACKSZ(NA, H), fc4_b, out_q, NA, ttab, tcount,
        perm, NA, H, 0);
}

// Round 8
// 227.453 us; speedup vs baseline: 1.1774x; 1.1774x over previous
//
#include <hip/hip_runtime.h>
#include <hip/hip_bf16.h>

typedef unsigned short ushort_t;
typedef __bf16 bf16x8 __attribute__((ext_vector_type(8)));
typedef unsigned short us8 __attribute__((ext_vector_type(8)));
typedef float f32x4 __attribute__((ext_vector_type(4)));

__device__ __forceinline__ float b2f(ushort_t h) {
    union { unsigned int u; float f; } v; v.u = ((unsigned int)h) << 16; return v.f;
}
__device__ __forceinline__ ushort_t f2b(float f) {
    union { float f; unsigned int u; } v; v.f = f;
    unsigned int u = v.u;
    unsigned int r = (u + 0x7FFFu + ((u >> 16) & 1u)) >> 16;
    return (ushort_t)r;
}
__device__ __forceinline__ float sigmoidf_(float x) {
    return 1.f / (1.f + __expf(-x));
}
__device__ __forceinline__ void store_o(ushort_t* p, float v) { *p = f2b(v); }
__device__ __forceinline__ void store_o(float* p, float v) { *p = v; }

__global__ void fill_kernel(float* out, long long n, float val) {
    long long i = (long long)blockIdx.x * blockDim.x + threadIdx.x;
    if (i < n) out[i] = val;
}

// ---------------------------------------------------------------------------
// Packed B layout for mfma_f32_16x16x32_bf16 (per 64-col block c, 32-k group
// kk): 4 col-subtiles su, 64 lanes (lane = k-oct*16 + col&15), 8 bf16.
// Tile (c,kk) = 2048 ushorts; wave fragment load = 1 KB contiguous.
// ---------------------------------------------------------------------------
#define PACKSZ(O, K) ((long long)((O) >= 64 ? (O) >> 6 : 1) * ((K) >> 5) * 2048)

// ---------------------------------------------------------------------------
// Ballot-based sort: 1 block, 1024 thr (16 waves x 512 elems). No atomic
// contention: per-wave histograms + in-wave ranks via ballot/popc.
// ---------------------------------------------------------------------------
__global__ void sort_kernel(const int* __restrict__ ids, int N,
                            int* __restrict__ perm, int* __restrict__ seg,
                            int4* __restrict__ ttab, int* __restrict__ tcount) {
    __shared__ int hist[16][8];
    __shared__ int wbase[16][8];
    __shared__ int atot[8];
    __shared__ int abase[8];
    int tid = threadIdx.x, wave = tid >> 6, lane = tid & 63;
    int base = wave * 512;
    unsigned long long lt = (lane == 63) ? 0x7fffffffffffffffull
                                         : ((1ull << lane) - 1ull);
    int myid[8], rank[8];
    int run[8] = {0, 0, 0, 0, 0, 0, 0, 0};
    #pragma unroll
    for (int i = 0; i < 8; i++) myid[i] = ids[base + i * 64 + lane] & 7;
    #pragma unroll
    for (int i = 0; i < 8; i++) {
        int a = myid[i];
        int r = 0;
        #pragma unroll
        for (int a2 = 0; a2 < 8; a2++) {
            unsigned long long m = __ballot(a == a2);
            if (a2 == a) r = run[a2] + __popcll(m & lt);
            run[a2] += __popcll(m);
        }
        rank[i] = r;
    }
    if (lane == 0) {
        #pragma unroll
        for (int a = 0; a < 8; a++) hist[wave][a] = run[a];
    }
    __syncthreads();
    if (tid < 8) {
        int a = tid, s = 0;
        for (int w = 0; w < 16; w++) { wbase[w][a] = s; s += hist[w][a]; }
        atot[a] = s;
    }
    __syncthreads();
    if (tid == 0) {
        int s = 0;
        for (int a = 0; a < 8; a++) { abase[a] = s; seg[a] = s; s += atot[a]; }
        seg[8] = s;
        int T = 0;
        for (int a = 0; a < 8; a++)
            for (int m = abase[a]; m < abase[a] + atot[a]; m += 64) {
                int e = abase[a] + atot[a];
                if (e > m + 64) e = m + 64;
                ttab[T++] = make_int4(a, m, e, 0);
            }
        *tcount = T;
    }
    __syncthreads();
    #pragma unroll
    for (int i = 0; i < 8; i++) {
        int a = myid[i];
        perm[abase[a] + wbase[wave][a] + rank[i]] = base + i * 64 + lane;
    }
}

// ---------------------------------------------------------------------------
// Fused prep: masked weights -> packed-B bf16; activations gathered to
// pos-order bf16; GRU weights -> packed-B bf16.
// ---------------------------------------------------------------------------
__device__ __forceinline__ void maskw_item(const float* __restrict__ alpha,
                                           const float* __restrict__ w,
                                           ushort_t* __restrict__ wm,
                                           long long idx, int O, int G, int dup) {
    int g = (int)(idx % G);
    long long t2 = idx / G;
    int o = (int)(t2 % O);
    int a = (int)(t2 / O);
    const float* al = alpha + idx * 6;
    float p[6];
    float mx = -1e30f;
    #pragma unroll
    for (int i = 0; i < 6; i++) { p[i] = al[i] * 0.2f; mx = fmaxf(mx, p[i]); }
    float s = 0.f;
    #pragma unroll
    for (int i = 0; i < 6; i++) { p[i] = __expf(p[i] - mx); s += p[i]; }
    float inv = 1.f / s;
    #pragma unroll
    for (int i = 0; i < 6; i++) p[i] *= inv;
    float mk[4] = { p[0] + p[1] + p[2], p[0] + p[3] + p[4],
                    p[1] + p[3] + p[5], p[2] + p[4] + p[5] };
    int K = G * 4;
    const float* wr = w + (long long)o * K + g * 4;
    ushort_t* base = wm + (long long)a * PACKSZ(O, K);
    int k0 = g * 4;
    int c = o >> 6, su = (o >> 4) & 3, n = o & 15;
    int kk = k0 >> 5, q = (k0 >> 3) & 3, e0 = k0 & 7;
    long long off = (((long long)(c * (K >> 5) + kk) * 4 + su) * 64 + (q * 16 + n)) * 8 + e0;
    #pragma unroll
    for (int t = 0; t < 4; t++) {
        ushort_t v = f2b(wr[t] * mk[t]);
        base[off + t] = v;
        if (dup) {
            base[off + t + 512] = v;
            base[off + t + 1024] = v;
            base[off + t + 1536] = v;
        }
    }
}

__device__ __forceinline__ void canon_gather_item(const float* __restrict__ src,
                                                  ushort_t* __restrict__ dst,
                                                  const int* __restrict__ perm,
                                                  int ld, long long i) {
    long long base = i * 8;
    int pos = (int)(base / ld);
    int k = (int)(base % ld);
    int row = perm[pos] & 8191;
    const float* s = src + (long long)row * ld + k;
    us8 v;
    #pragma unroll
    for (int e = 0; e < 8; e++) v[e] = f2b(s[e]);
    *(us8*)(dst + base) = v;
}

__device__ __forceinline__ void canon_pack_item(const float* __restrict__ src,
                                                ushort_t* __restrict__ dst,
                                                long long i) {
    long long base = i * 8;
    int o_full = (int)(base >> 9);
    int k0 = (int)(base & 511);
    int g = o_full >> 9, o = o_full & 511;
    int c = o >> 6, su = (o >> 4) & 3, n = o & 15;
    int kk = k0 >> 5, q = (k0 >> 3) & 3;
    long long off = (long long)g * 262144 +
        (((long long)(c * 16 + kk) * 4 + su) * 64 + (q * 16 + n)) * 8;
    us8 v;
    #pragma unroll
    for (int e = 0; e < 8; e++) v[e] = f2b(src[base + e]);
    *(us8*)(dst + off) = v;
}

#define PB0 256
#define PB1 2048
#define PB2 2048
#define PB3 64
#define PB4 256
#define PB5 2048
#define PB6 384
#define PB7 384
#define PREP_BLOCKS (PB0+PB1+PB2+PB3+PB4+PB5+PB6+PB7)

__global__ void prep_kernel(const float* fc1_al, const float* fc1_w, ushort_t* wm1,
                            const float* fc2_al, const float* fc2_w, ushort_t* wm2,
                            const float* fc3_al, const float* fc3_w, ushort_t* wm3,
                            const float* fc4_al, const float* fc4_w, ushort_t* wm4,
                            const float* inputs, ushort_t* inp_pos,
                            const float* hidden, ushort_t* hid_pos,
                            const float* wih, ushort_t* wihp,
                            const float* whh, ushort_t* whhp,
                            const int* perm) {
    int b = blockIdx.x;
    int tid = threadIdx.x;
    if (b < PB0) { maskw_item(fc1_al, fc1_w, wm1, (long long)b * 256 + tid, 512, 16, 0); return; }
    b -= PB0;
    if (b < PB1) { maskw_item(fc2_al, fc2_w, wm2, (long long)b * 256 + tid, 512, 128, 0); return; }
    b -= PB1;
    if (b < PB2) { maskw_item(fc3_al, fc3_w, wm3, (long long)b * 256 + tid, 512, 128, 0); return; }
    b -= PB2;
    if (b < PB3) { maskw_item(fc4_al, fc4_w, wm4, (long long)b * 256 + tid, 16, 128, 1); return; }
    b -= PB3;
    if (b < PB4) { canon_gather_item(inputs, inp_pos, perm, 64, (long long)b * 256 + tid); return; }
    b -= PB4;
    if (b < PB5) { canon_gather_item(hidden, hid_pos, perm, 512, (long long)b * 256 + tid); return; }
    b -= PB5;
    if (b < PB6) { canon_pack_item(wih, wihp, (long long)b * 256 + tid); return; }
    b -= PB6;
    canon_pack_item(whh, whhp, (long long)b * 256 + tid);
}

// ---------------------------------------------------------------------------
// GEMM: A staged via swizzled LDS; B streamed from packed global (L2).
// ---------------------------------------------------------------------------
#define BM 64
#define BN 64

template <typename OT>
__launch_bounds__(256, 4)
__global__ void gemm_tiled(const ushort_t* __restrict__ In, int ldin,
                           const ushort_t* __restrict__ Wpk, long long wstride,
                           const float* __restrict__ bias,
                           OT* __restrict__ Out, int ldo,
                           const int4* __restrict__ ttab,
                           const int* __restrict__ tcount,
                           const int* __restrict__ scatter,
                           int O, int K, int relu) {
    int t = blockIdx.x;
    if (t >= *tcount) return;
    int4 tt = ttab[t];
    int a = tt.x, pos0 = tt.y, pos1 = tt.z;
    int o0 = blockIdx.y * BN;

    __shared__ ushort_t As[2048];

    int tid = threadIdx.x;
    int wave = tid >> 6, lane = tid & 63;
    int wr = (wave >> 1) & 1, wc = wave & 1;
    int quad = lane >> 4, l16 = lane & 15;
    int srow = tid >> 2, sgrp = tid & 3;
    int wsoff = (srow * 4 + (sgrp ^ ((srow >> 2) & 3))) * 8;
    int rl = (l16 * 4 + (quad ^ ((l16 >> 2) & 3))) * 8;

    int apos = pos0 + srow;
    int apos_c = apos < pos1 ? apos : (pos1 - 1);
    const ushort_t* aptr = In + (long long)apos_c * ldin + sgrp * 8;

    const ushort_t* wb = Wpk + (long long)a * wstride +
        (long long)blockIdx.y * (K >> 5) * 2048 + lane * 8;

    f32x4 acc[2][2];
    #pragma unroll
    for (int i = 0; i < 2; i++)
        #pragma unroll
        for (int j = 0; j < 2; j++) acc[i][j] = (f32x4){0.f, 0.f, 0.f, 0.f};

    int KK = K >> 5;
    for (int kk = 0; kk < KK; kk++) {
        us8 av = *(const us8*)(aptr + kk * 32);
        bf16x8 bfr[2];
        bfr[0] = *(const bf16x8*)(wb + (kk * 4 + wc * 2 + 0) * 512);
        bfr[1] = *(const bf16x8*)(wb + (kk * 4 + wc * 2 + 1) * 512);
        __syncthreads();
        *(us8*)(&As[wsoff]) = av;
        __syncthreads();
        bf16x8 af[2];
        af[0] = *(const bf16x8*)(&As[(wr * 2 + 0) * 512 + rl]);
        af[1] = *(const bf16x8*)(&As[(wr * 2 + 1) * 512 + rl]);
        #pragma unroll
        for (int i = 0; i < 2; i++)
            #pragma unroll
            for (int j = 0; j < 2; j++)
                acc[i][j] = __builtin_amdgcn_mfma_f32_16x16x32_bf16(af[i], bfr[j], acc[i][j], 0, 0, 0);
    }

    #pragma unroll
    for (int i = 0; i < 2; i++) {
        int mbase = wr * 32 + i * 16 + quad * 4;
        #pragma unroll
        for (int j = 0; j < 2; j++) {
            int col = o0 + wc * 32 + j * 16 + l16;
            if (col < O) {
                float bias_v = bias ? bias[col] : 0.f;
                #pragma unroll
                for (int r = 0; r < 4; r++) {
                    int pos = pos0 + mbase + r;
                    if (pos < pos1) {
                        float v = acc[i][j][r] + bias_v;
                        if (relu) v = fmaxf(v, 0.f);
                        int orow = (scatter ? scatter[pos] : pos) & 8191;
                        store_o(&Out[(long long)orow * ldo + col], v);
                    }
                }
            }
        }
    }
}

// ---------------------------------------------------------------------------
// Fused GRU, 4 accumulator groups (r/z gates sum both GEMMs into one acc):
//   acc0 = y1.wih_r + h.whh_r ; acc1 = y1.wih_z + h.whh_z
//   acc2 = y1.wih_n           ; acc3 = h.whh_n
// 64 AGPR acc -> 3 waves/SIMD. A via swizzled LDS; B staged LDS from packed
// global (straight copy, conflict-free), reused by both wr-waves.
// ---------------------------------------------------------------------------
__launch_bounds__(256, 3)
__global__ void gru_fused(const ushort_t* __restrict__ y1,       // [N,H] pos bf16
                          const ushort_t* __restrict__ hid_pos,  // [N,H] pos bf16
                          const float* __restrict__ hidden_f,    // [N,H] orig fp32
                          const ushort_t* __restrict__ wihp,     // packed 3x(512,512)
                          const ushort_t* __restrict__ whhp,     // packed 3x(512,512)
                          const float* __restrict__ bih,
                          const float* __restrict__ bhh,
                          const int* __restrict__ perm,
                          float* __restrict__ out_h_f,           // [N,H] orig fp32
                          ushort_t* __restrict__ hp,             // [N,H] pos bf16
                          int N, int H) {
    int m0 = blockIdx.x * 64;

    __shared__ ushort_t Ay[2048];
    __shared__ ushort_t Ah[2048];
    __shared__ ushort_t Bt[6][2048];

    int tid = threadIdx.x;
    int wave = tid >> 6, lane = tid & 63;
    int wr = (wave >> 1) & 1, wc = wave & 1;
    int quad = lane >> 4, l16 = lane & 15;
    int srow = tid >> 2, sgrp = tid & 3;
    int wsoff = (srow * 4 + (sgrp ^ ((srow >> 2) & 3))) * 8;
    int rl = (l16 * 4 + (quad ^ ((l16 >> 2) & 3))) * 8;

    const ushort_t* ay_p = y1 + (long long)(m0 + srow) * H + sgrp * 8;
    const ushort_t* ah_p = hid_pos + (long long)(m0 + srow) * H + sgrp * 8;

    // packed B tile stream bases (c-block = blockIdx.y): tile(kk) at kk*2048
    long long cb = (long long)blockIdx.y * 16 * 2048 + tid * 8;
    const ushort_t* wbg[6];
    #pragma unroll
    for (int g = 0; g < 3; g++) wbg[g] = wihp + (long long)g * 262144 + cb;
    #pragma unroll
    for (int g = 3; g < 6; g++) wbg[g] = whhp + (long long)(g - 3) * 262144 + cb;

    f32x4 acc[4][2][2];
    #pragma unroll
    for (int g = 0; g < 4; g++)
        #pragma unroll
        for (int i = 0; i < 2; i++)
            #pragma unroll
            for (int j = 0; j < 2; j++) acc[g][i][j] = (f32x4){0.f, 0.f, 0.f, 0.f};

    for (int kk = 0; kk < 16; kk++) {
        us8 va = *(const us8*)(ay_p + kk * 32);
        us8 vh = *(const us8*)(ah_p + kk * 32);
        us8 vb[6];
        #pragma unroll
        for (int g = 0; g < 6; g++) vb[g] = *(const us8*)(wbg[g] + kk * 2048);
        __syncthreads();
        *(us8*)(&Ay[wsoff]) = va;
        *(us8*)(&Ah[wsoff]) = vh;
        #pragma unroll
        for (int g = 0; g < 6; g++) *(us8*)(&Bt[g][tid * 8]) = vb[g];
        __syncthreads();

        bf16x8 ayf[2], ahf[2];
        #pragma unroll
        for (int u = 0; u < 2; u++) {
            ayf[u] = *(const bf16x8*)(&Ay[(wr * 2 + u) * 512 + rl]);
            ahf[u] = *(const bf16x8*)(&Ah[(wr * 2 + u) * 512 + rl]);
        }
        #pragma unroll
        for (int g = 0; g < 3; g++) {
            bf16x8 bw[2], bu[2];
            #pragma unroll
            for (int u = 0; u < 2; u++) {
                bw[u] = *(const bf16x8*)(&Bt[g][(wc * 2 + u) * 512 + lane * 8]);
                bu[u] = *(const bf16x8*)(&Bt[g + 3][(wc * 2 + u) * 512 + lane * 8]);
            }
            int ai = (g < 2) ? g : 2;   // ih products: r->0, z->1, n->2
            int ah2 = (g < 2) ? g : 3;  // hh products: r->0, z->1, n->3
            #pragma unroll
            for (int i = 0; i < 2; i++)
                #pragma unroll
                for (int j = 0; j < 2; j++) {
                    acc[ai][i][j] = __builtin_amdgcn_mfma_f32_16x16x32_bf16(
                        ayf[i], bw[j], acc[ai][i][j], 0, 0, 0);
                    acc[ah2][i][j] = __builtin_amdgcn_mfma_f32_16x16x32_bf16(
                        ahf[i], bu[j], acc[ah2][i][j], 0, 0, 0);
                }
        }
    }

    int c0 = blockIdx.y * 64;
    #pragma unroll
    for (int i = 0; i < 2; i++) {
        #pragma unroll
        for (int r = 0; r < 4; r++) {
            int pos = m0 + wr * 32 + i * 16 + quad * 4 + r;
            int norig = perm[pos] & 8191;
            #pragma unroll
            for (int j = 0; j < 2; j++) {
                int col = c0 + wc * 32 + j * 16 + l16;
                float sr = acc[0][i][j][r] + bih[col] + bhh[col];
                float sz = acc[1][i][j][r] + bih[H + col] + bhh[H + col];
                float in_ = acc[2][i][j][r] + bih[2 * H + col];
                float hn = acc[3][i][j][r] + bhh[2 * H + col];
                float rg = sigmoidf_(sr);
                float zg = sigmoidf_(sz);
                float ng = tanhf(in_ + rg * hn);
                float hv = hidden_f[(long long)norig * H + col];
                float hnew = (1.f - zg) * ng + zg * hv;
                out_h_f[(long long)norig * H + col] = hnew;
                hp[(long long)pos * H + col] = f2b(hnew);
            }
        }
    }
}

// ---------------------------------------------------------------------------
extern "C" void kernel_launch(void* const* d_in, const int* in_sizes, int n_in,
                              void* d_out, int out_size, void* d_ws, size_t ws_size,
                              hipStream_t stream) {
    (void)in_sizes; (void)n_in;
    const int N = 8192, A = 8, E = 64, H = 512, NA = 16;

    float* out_f = (float*)d_out;
    float* out_q = out_f;                        // [N, NA] fp32
    float* out_h = out_f + (size_t)N * NA;       // [N, H] fp32, original order

    char* p = (char*)d_ws;
    auto alloc = [&](size_t b) { char* r = p; p += (b + 255) & ~(size_t)255; return r; };
    int*  perm   = (int*)alloc((size_t)N * 4);
    int*  seg    = (int*)alloc(16 * 4);
    int4* ttab   = (int4*)alloc(144 * 16);
    int*  tcount = (int*)alloc(256);
    ushort_t* wm1     = (ushort_t*)alloc((size_t)A * PACKSZ(H, E) * 2);
    ushort_t* wm2     = (ushort_t*)alloc((size_t)A * PACKSZ(H, H) * 2);
    ushort_t* wm3     = (ushort_t*)alloc((size_t)A * PACKSZ(H, H) * 2);
    ushort_t* wm4     = (ushort_t*)alloc((size_t)A * PACKSZ(NA, H) * 2);
    ushort_t* y1      = (ushort_t*)alloc((size_t)N * H * 2);
    ushort_t* inp_pos = (ushort_t*)alloc((size_t)N * E * 2);
    ushort_t* hid_pos = (ushort_t*)alloc((size_t)N * H * 2);
    ushort_t* wihp    = (ushort_t*)alloc((size_t)3 * H * H * 2);
    ushort_t* whhp    = (ushort_t*)alloc((size_t)3 * H * H * 2);
    ushort_t* hp      = (ushort_t*)alloc((size_t)N * H * 2);
    size_t need = (size_t)(p - (char*)d_ws);
    ushort_t* q2 = y1;       // alias: y1 dead after gru_fused
    ushort_t* q3 = hid_pos;  // alias: hid_pos dead after gru_fused

    if (ws_size < need) {
        fill_kernel<<<(unsigned)((out_size + 255) / 256), 256, 0, stream>>>(
            out_f, out_size, 1000.f);
        return;
    }

    const float* inputs = (const float*)d_in[0];
    const float* hidden = (const float*)d_in[1];
    const int*   ids    = (const int*)d_in[2];
    const float* fc1_w  = (const float*)d_in[3];
    const float* fc1_b  = (const float*)d_in[4];
    const float* fc1_al = (const float*)d_in[5];
    const float* wih    = (const float*)d_in[6];
    const float* whh    = (const float*)d_in[7];
    const float* bih    = (const float*)d_in[8];
    const float* bhh    = (const float*)d_in[9];
    const float* fc2_w  = (const float*)d_in[10];
    const float* fc2_b  = (const float*)d_in[11];
    const float* fc2_al = (const float*)d_in[12];
    const float* fc3_w  = (const float*)d_in[13];
    const float* fc3_b  = (const float*)d_in[14];
    const float* fc3_al = (const float*)d_in[15];
    const float* fc4_w  = (const float*)d_in[16];
    const float* fc4_b  = (const float*)d_in[17];
    const float* fc4_al = (const float*)d_in[18];

    sort_kernel<<<1, 1024, 0, stream>>>(ids, N, perm, seg, ttab, tcount);

    prep_kernel<<<PREP_BLOCKS, 256, 0, stream>>>(
        fc1_al, fc1_w, wm1, fc2_al, fc2_w, wm2, fc3_al, fc3_w, wm3,
        fc4_al, fc4_w, wm4, inputs, inp_pos, hidden, hid_pos,
        wih, wihp, whh, whhp, perm);

    dim3 blk(256);
    gemm_tiled<ushort_t><<<dim3(136, H / BN), blk, 0, stream>>>(
        inp_pos, E, wm1, PACKSZ(H, E), fc1_b, y1, H, ttab, tcount,
        nullptr, H, E, 1);
    gru_fused<<<dim3(N / 64, H / 64), blk, 0, stream>>>(
        y1, hid_pos, hidden, wihp, whhp, bih, bhh, perm, out_h, hp, N, H);
    gemm_tiled<ushort_t><<<dim3(136, H / BN), blk, 0, stream>>>(
        hp, H, wm2, PACKSZ(H, H), fc2_b, q2, H, ttab, tcount,
        nullptr, H, H, 1);
    gemm_tiled<ushort_t><<<dim3(136, H / BN), blk, 0, stream>>>(
        q2, H, wm3, PACKSZ(H, H), fc3_b, q3, H, ttab, tcount,
        nullptr, H, H, 1);
    gemm_tiled<float><<<dim3(136, 1), blk, 0, stream>>>(
        q3, H, wm4, PACKSZ(NA, H), fc4_b, out_q, NA, ttab, tcount,
        perm, NA, H, 0);
}